// Round 14
// baseline (198.331 us; speedup 1.0000x reference)
//
#include <hip/hip_runtime.h>

#define DIMN 32
#define HD   32
#define FN   16
#define FE   8
#define NG   64
#define CAP  64          // bucket capacity (in-degree ~Poisson(16); fallback below)
#define BLK  512         // 8 waves/block
#define GRID 512         // 2 blocks/CU guaranteed (LDS would allow 3 -> slack)
#define KW   8           // waves per block
#define NPU  16          // nodes per unit (8 waves x 2 iterations)

// Grid phase barrier, atomics-only (NO threadfence / L2 writeback — R4 lesson):
// each thread drains its own vmem queue (its atomics are then visible at the
// memory-side coherence point), then thread 0 signals and RMW-polls.
__device__ __forceinline__ void phase_barrier(int* cnt, int target) {
    asm volatile("s_waitcnt vmcnt(0)" ::: "memory");
    __syncthreads();
    if (threadIdx.x == 0) {
        atomicAdd(cnt, 1);
        while (atomicAdd(cnt, 0) < target)
            __builtin_amdgcn_s_sleep(16);
    }
    __syncthreads();
}

#define EDGE_FMA(o, a) \
    S += (o); \
    T0 = fmaf((o), (a).x, T0);  T1 = fmaf((o), (a).y, T1); \
    T2 = fmaf((o), (a).z, T2);  T3 = fmaf((o), (a).w, T3);

#define CONTRIB(DD, A) { \
    const int d_ = d0 + (DD); \
    const float4 ta_ = *(const float4*)&s_T[w * 256 + d_ * 8]; \
    const float4 tb_ = *(const float4*)&s_T[w * 256 + d_ * 8 + 4]; \
    const float2 so_ = s_SO[w * 32 + d_]; \
    const int b_ = d_ * 256 + h; \
    A = fmaf(ta_.x, s_nnw2[b_      ], A); \
    A = fmaf(ta_.y, s_nnw2[b_ +  32], A); \
    A = fmaf(ta_.z, s_nnw2[b_ +  64], A); \
    A = fmaf(ta_.w, s_nnw2[b_ +  96], A); \
    A = fmaf(tb_.x, s_nnw2[b_ + 128], A); \
    A = fmaf(tb_.y, s_nnw2[b_ + 160], A); \
    A = fmaf(tb_.z, s_nnw2[b_ + 192], A); \
    A = fmaf(tb_.w, s_nnw2[b_ + 224], A); \
    A = fmaf(so_.x, s_nnb[d_ * 32 + h], A); \
    A = fmaf(so_.y, s_rw [d_ * 32 + h], A); }

// One persistent kernel: A(out+zero) / B(bucket) / C(gather, R12-proven body) /
// D(head). ALL cross-phase data flows through device-scope atomics (memory-side,
// XCD-coherent); normal reads of it are safe because no XCD caches those lines
// before its first post-write touch (atomics don't allocate into L1/L2/K$).
__global__ __launch_bounds__(BLK, 4) void mega_fused(
    const float* __restrict__ x, const int* __restrict__ ei,
    const float* __restrict__ ea, const int* __restrict__ batch,
    const float* __restrict__ lin0_w, const float* __restrict__ lin0_b,
    const float* __restrict__ nn_w, const float* __restrict__ nn_b,
    const float* __restrict__ root_w, const float* __restrict__ conv_b,
    const float* __restrict__ lin1_w, const float* __restrict__ lin1_b,
    const float* __restrict__ lin2_w, const float* __restrict__ lin2_b,
    float* __restrict__ outn, float* __restrict__ aggfb, float* __restrict__ u,
    int* __restrict__ deg, unsigned long long* __restrict__ esll,
    int* __restrict__ cnt, float* __restrict__ outp, int N, int E)
{
    __shared__ float  s_nnw2[DIMN * FE * HD];  // 32 KB
    __shared__ float  s_nnb[DIMN * HD];        // 4 KB
    __shared__ float  s_rw[DIMN * HD];         // 4 KB
    __shared__ float  s_cb[HD];
    __shared__ float  s_T[KW * 256];           // 8 KB
    __shared__ float2 s_SO[KW * 32];           // 2 KB
    __shared__ float  s_V[KW * 32];            // 1 KB
    __shared__ int    s_G[KW];

    const int tid = threadIdx.x;

    // Stage phase-C weights NOW (inputs only) — latency hides under phase A.
    for (int i = tid; i < DIMN * FE * HD; i += BLK) {
        const int d = i >> 8, rem = i & 255, hh = rem >> 3, f = rem & 7;
        s_nnw2[(d * 8 + f) * 32 + hh] = nn_w[i];   // nn_w[i] = nn_w[(d*32+hh)*8+f]
    }
    for (int i = tid; i < DIMN * HD; i += BLK) { s_nnb[i] = nn_b[i]; s_rw[i] = root_w[i]; }
    if (tid < HD) s_cb[tid] = conv_b[tid];

    // ---- Phase A: out = relu(x@lin0_w^T+b); zero aggfb/deg/u (all atomics) ----
    for (int gt = blockIdx.x * BLK + tid; gt < N * DIMN; gt += GRID * BLK) {
        const int n = gt >> 5, d = gt & 31;
        float s = lin0_b[d];
        const float* xr = x + (size_t)n * FN;
        const float* wr = lin0_w + d * FN;
        #pragma unroll
        for (int j = 0; j < FN; ++j) s = fmaf(xr[j], wr[j], s);
        atomicExch(&outn[gt], fmaxf(s, 0.f));
        atomicExch(&aggfb[gt], 0.f);
        if (d == 0) atomicExch(&deg[n], 0);
    }
    if (blockIdx.x == 0)
        for (int i = tid; i < NG * HD; i += BLK) atomicExch(&u[i], 0.f);

    phase_barrier(cnt, GRID);

    // ---- Phase B: bucket edges by dst: esll[dst*CAP+pos] = {src,e} packed ----
    for (int e = blockIdx.x * BLK + tid; e < E; e += GRID * BLK) {
        const int src = ei[e];
        const int dst = ei[E + e];
        const int pos = atomicAdd(&deg[dst], 1);
        if (pos < CAP) {
            atomicExch(&esll[(size_t)dst * CAP + pos],
                       ((unsigned long long)(unsigned)src << 32) | (unsigned)e);
        } else {   // statistically never (Poisson(16) vs CAP=64)
            float ef[FE];
            #pragma unroll
            for (int f = 0; f < FE; ++f) ef[f] = ea[(size_t)e * FE + f];
            for (int hh = 0; hh < HD; ++hh) {
                float m = 0.f;
                for (int d = 0; d < DIMN; ++d) {
                    float wdh = nn_b[d * HD + hh];
                    #pragma unroll
                    for (int f = 0; f < FE; ++f)
                        wdh = fmaf(ef[f], nn_w[(d * HD + hh) * FE + f], wdh);
                    m = fmaf(outn[(size_t)src * DIMN + d], wdh, m);
                }
                atomicAdd(aggfb + (size_t)dst * HD + hh, m);
            }
        }
    }
    phase_barrier(cnt, 2 * GRID);

    // ---- Phase C: R12-proven gather (chunk-8, one node/wave, 2 it/unit) ----
    const int l = tid & 63;
    const int h = l & 31;
    const int p = l >> 5;
    const int w = tid >> 6;
    const int nunits = (N + NPU - 1) / NPU;

    for (int unit = blockIdx.x; unit < nunits; unit += GRID) {
        float accp  = 0.f;
        int   g_cur = -1;
        for (int it = 0; it < 2; ++it) {
            const int n = unit * NPU + it * KW + w;
            int gval = -1;
            if (n < N) {
                const int nu = __builtin_amdgcn_readfirstlane(n);
                const int dn = min(deg[nu], CAP);            // uniform -> s_load
                const unsigned long long* ep = esll + (size_t)nu * CAP;
                const int f0 = 4 * p;

                float T0 = 0.f, T1 = 0.f, T2 = 0.f, T3 = 0.f, S = 0.f;

                for (int j0 = 0; j0 < dn; j0 += 8) {
                    const int jm = dn - 1;
                    const unsigned long long q0 = ep[j0];
                    const unsigned long long q1 = ep[min(j0 + 1, jm)];
                    const unsigned long long q2 = ep[min(j0 + 2, jm)];
                    const unsigned long long q3 = ep[min(j0 + 3, jm)];
                    const unsigned long long q4 = ep[min(j0 + 4, jm)];
                    const unsigned long long q5 = ep[min(j0 + 5, jm)];
                    const unsigned long long q6 = ep[min(j0 + 6, jm)];
                    const unsigned long long q7 = ep[min(j0 + 7, jm)];
                    const int e0 = (int)(unsigned)q0, s0 = (int)(q0 >> 32);
                    const int e1 = (int)(unsigned)q1, s1 = (int)(q1 >> 32);
                    const int e2 = (int)(unsigned)q2, s2 = (int)(q2 >> 32);
                    const int e3 = (int)(unsigned)q3, s3 = (int)(q3 >> 32);
                    const int e4 = (int)(unsigned)q4, s4 = (int)(q4 >> 32);
                    const int e5 = (int)(unsigned)q5, s5 = (int)(q5 >> 32);
                    const int e6 = (int)(unsigned)q6, s6 = (int)(q6 >> 32);
                    const int e7 = (int)(unsigned)q7, s7 = (int)(q7 >> 32);

                    const float4 a0 = *(const float4*)(ea + (size_t)e0 * FE + f0);
                    const float4 a1 = *(const float4*)(ea + (size_t)e1 * FE + f0);
                    const float4 a2 = *(const float4*)(ea + (size_t)e2 * FE + f0);
                    const float4 a3 = *(const float4*)(ea + (size_t)e3 * FE + f0);
                    const float4 a4 = *(const float4*)(ea + (size_t)e4 * FE + f0);
                    const float4 a5 = *(const float4*)(ea + (size_t)e5 * FE + f0);
                    const float4 a6 = *(const float4*)(ea + (size_t)e6 * FE + f0);
                    const float4 a7 = *(const float4*)(ea + (size_t)e7 * FE + f0);
                    float o0 = outn[(size_t)s0 * DIMN + h];
                    float o1 = outn[(size_t)s1 * DIMN + h];
                    float o2 = outn[(size_t)s2 * DIMN + h];
                    float o3 = outn[(size_t)s3 * DIMN + h];
                    float o4 = outn[(size_t)s4 * DIMN + h];
                    float o5 = outn[(size_t)s5 * DIMN + h];
                    float o6 = outn[(size_t)s6 * DIMN + h];
                    float o7 = outn[(size_t)s7 * DIMN + h];

                    o1 = (j0 + 1 <= jm) ? o1 : 0.f;
                    o2 = (j0 + 2 <= jm) ? o2 : 0.f;
                    o3 = (j0 + 3 <= jm) ? o3 : 0.f;
                    o4 = (j0 + 4 <= jm) ? o4 : 0.f;
                    o5 = (j0 + 5 <= jm) ? o5 : 0.f;
                    o6 = (j0 + 6 <= jm) ? o6 : 0.f;
                    o7 = (j0 + 7 <= jm) ? o7 : 0.f;

                    EDGE_FMA(o0, a0) EDGE_FMA(o1, a1) EDGE_FMA(o2, a2) EDGE_FMA(o3, a3)
                    EDGE_FMA(o4, a4) EDGE_FMA(o5, a5) EDGE_FMA(o6, a6) EDGE_FMA(o7, a7)
                }

                *(float4*)&s_T[w * 256 + h * 8 + f0] = make_float4(T0, T1, T2, T3);
                if (p == 0) s_SO[w * 32 + h] = make_float2(S, outn[(size_t)nu * DIMN + h]);
                // Same-wave LDS write->read: lockstep + compiler lgkmcnt orders this.

                const float base = aggfb[(size_t)nu * HD + h] + s_cb[h];

                float acc0 = 0.f, acc1 = 0.f, acc2 = 0.f, acc3 = 0.f;
                const int d0 = p << 4;
                #pragma unroll
                for (int dd = 0; dd < 16; dd += 4) {
                    CONTRIB(dd + 0, acc0)
                    CONTRIB(dd + 1, acc1)
                    CONTRIB(dd + 2, acc2)
                    CONTRIB(dd + 3, acc3)
                }
                float acc = (acc0 + acc1) + (acc2 + acc3);
                acc += __shfl_xor(acc, 32);

                const float v = fmaxf(acc + base, 0.f);
                if (p == 0) s_V[w * 32 + h] = v;
                gval = batch[nu];
            }
            if (l == 0) s_G[w] = gval;
            __syncthreads();

            if (tid < 32) {
                #pragma unroll
                for (int ww = 0; ww < KW; ++ww) {
                    const int gg = s_G[ww];
                    if (gg >= 0) {
                        const float vv = s_V[ww * 32 + tid];
                        if (gg != g_cur) {
                            if (g_cur >= 0) atomicAdd(u + (size_t)g_cur * HD + tid, accp);
                            g_cur = gg;
                            accp = vv;
                        } else {
                            accp += vv;
                        }
                    }
                }
            }
            __syncthreads();
        }
        if (tid < 32 && g_cur >= 0) atomicAdd(u + (size_t)g_cur * HD + tid, accp);
    }
    phase_barrier(cnt, 3 * GRID);

    // ---- Phase D: head (block 0; u read via returning atomics, R7-proven) ----
    if (blockIdx.x == 0 && tid < NG) {
        const int g = tid;
        float ur[HD];
        #pragma unroll
        for (int hh = 0; hh < HD; ++hh)
            ur[hh] = atomicAdd(&u[(size_t)g * HD + hh], 0.f);
        float acc2 = lin2_b[0];
        #pragma unroll
        for (int i = 0; i < 16; ++i) {
            float o = lin1_b[i];
            #pragma unroll
            for (int hh = 0; hh < HD; ++hh)
                o = fmaf(ur[hh], lin1_w[i * HD + hh], o);
            o = fmaxf(o, 0.f);
            acc2 = fmaf(o, lin2_w[i], acc2);
        }
        outp[g] = acc2;
    }
}

extern "C" void kernel_launch(void* const* d_in, const int* in_sizes, int n_in,
                              void* d_out, int out_size, void* d_ws, size_t ws_size,
                              hipStream_t stream)
{
    const float* x      = (const float*)d_in[0];
    const int*   ei     = (const int*)  d_in[1];
    const float* ea     = (const float*)d_in[2];
    const int*   batch  = (const int*)  d_in[3];
    const float* lin0_w = (const float*)d_in[4];
    const float* lin0_b = (const float*)d_in[5];
    const float* nn_w   = (const float*)d_in[6];
    const float* nn_b   = (const float*)d_in[7];
    const float* root_w = (const float*)d_in[8];
    const float* conv_b = (const float*)d_in[9];
    const float* lin1_w = (const float*)d_in[10];
    const float* lin1_b = (const float*)d_in[11];
    const float* lin2_w = (const float*)d_in[12];
    const float* lin2_b = (const float*)d_in[13];

    const int N = in_sizes[0] / FN;   // 12500
    const int E = in_sizes[2] / FE;   // 200000

    // Layout: cnt(16 ints) | outn | aggfb | u | deg | esll (8B-aligned: all
    // preceding counts are even).
    int*   cnt   = (int*)d_ws;
    float* outn  = (float*)d_ws + 16;              // N*32
    float* aggfb = outn  + (size_t)N * DIMN;       // N*32
    float* u     = aggfb + (size_t)N * DIMN;       // 64*32
    int*   deg   = (int*)(u + (size_t)NG * HD);    // N (even)
    unsigned long long* esll = (unsigned long long*)(deg + N);   // N*CAP

    hipMemsetAsync(cnt, 0, 64, stream);   // barrier counter (poisoned each iter)

    mega_fused<<<GRID, BLK, 0, stream>>>(
        x, ei, ea, batch, lin0_w, lin0_b, nn_w, nn_b, root_w, conv_b,
        lin1_w, lin1_b, lin2_w, lin2_b,
        outn, aggfb, u, deg, esll, cnt, (float*)d_out, N, E);
}